// Round 2
// baseline (343.873 us; speedup 1.0000x reference)
//
#include <hip/hip_runtime.h>
#include <math.h>

// Problem constants (fixed by the reference).
#define BSZ  2
#define DOPN 32
#define RAN  128   // D (z)
#define AZI  128   // H (y)
#define ELE  32    // W (x)
#define NVOX (RAN * AZI * ELE)   // 524288 voxels per batch
#define TPB  256
#define VPT  4     // voxels per thread in kernel B (float4-wide streaming)
#define DH   8     // DOP chunk size (8 float4 x1 + 8 float4 gumbels in flight)

__device__ __forceinline__ float sigmoidf_(float t) {
    return 1.0f / (1.0f + __expf(-t));
}

// Kernel A: xyz4[b][n] = {x,y,z,0} cartesian of coords. Interleaved float4 so
// kernel B's 8-corner gather is 8x float4 instead of 24 scalar loads.
// VPT=4: float4 in / 4x float4 out halves VMEM instruction count.
__global__ __launch_bounds__(TPB) void xyz_precompute(
    const float* __restrict__ coords, float4* __restrict__ xyz4)
{
    const int n0 = (blockIdx.x * TPB + threadIdx.x) * 4;
    const int b = blockIdx.y;
    const float* cb = coords + (size_t)b * 3 * NVOX;
    const float4 r4 = *(const float4*)(cb + n0);
    const float4 a4 = *(const float4*)(cb + NVOX + n0);
    const float4 e4 = *(const float4*)(cb + 2 * NVOX + n0);
    const float rr[4] = { r4.x, r4.y, r4.z, r4.w };
    const float aa[4] = { a4.x, a4.y, a4.z, a4.w };
    const float ee[4] = { e4.x, e4.y, e4.z, e4.w };
    float4* op = xyz4 + (size_t)b * NVOX + n0;
    #pragma unroll
    for (int v = 0; v < 4; ++v) {
        float sa, ca, se, ce;
        __sincosf(aa[v], &sa, &ca);
        __sincosf(ee[v], &se, &ce);
        op[v] = make_float4(rr[v] * ce * ca, rr[v] * ce * sa, rr[v] * se, 0.0f);
    }
}

// Kernel B: per-voxel DOP reduction (argmax of x1+gumbels, softmax(x1)·dop)
// + trilinear warp + loss. VPT=4 with float4 loads: the kernel is
// VMEM-instruction-issue bound (rocprof: 13% VALU, 18% HBM), so halving the
// load-instruction count per voxel is the lever. DOP loads burst in chunks
// of 8 planes (16 outstanding float4 loads) to bound register pressure.
__global__ __launch_bounds__(TPB) void seg_dop_loss(
    const float* __restrict__ seg, const float* __restrict__ flow,
    const float* __restrict__ x1, const float* __restrict__ dop_arr,
    const float* __restrict__ ori, const float* __restrict__ gumbels,
    const float4* __restrict__ xyz4, float* __restrict__ out)
{
    __shared__ float s_dop[DOPN];
    __shared__ float s_wave[TPB / 64];

    const int b = blockIdx.y;
    if (threadIdx.x < DOPN) s_dop[threadIdx.x] = dop_arr[b * DOPN + threadIdx.x];
    __syncthreads();

    const int n0 = (blockIdx.x * TPB + threadIdx.x) * VPT;
    const size_t base = (size_t)b * DOPN * NVOX + (size_t)n0;

    // ---- DOP axis: argmax(x1+gumbels) + unnormalized softmax(x1)·dop ----
    // x1 ~ N(0,1): exp without max-subtraction is fp32-safe and exact here.
    // Track the dop VALUE at the running max (first-max semantics == argmax).
    float m_lg[VPT] = { -3.4e38f, -3.4e38f, -3.4e38f, -3.4e38f };
    float mdop[VPT] = { 0.f, 0.f, 0.f, 0.f };
    float ssum[VPT] = { 0.f, 0.f, 0.f, 0.f };
    float wsum[VPT] = { 0.f, 0.f, 0.f, 0.f };

    for (int h = 0; h < DOPN / DH; ++h) {           // runtime loop: regs reused
        const size_t dbase = base + (size_t)h * DH * NVOX;
        float4 xa[DH], ga[DH];
        #pragma unroll
        for (int d = 0; d < DH; ++d)
            xa[d] = *(const float4*)(x1 + dbase + (size_t)d * NVOX);
        #pragma unroll
        for (int d = 0; d < DH; ++d)
            ga[d] = *(const float4*)(gumbels + dbase + (size_t)d * NVOX);
        #pragma unroll
        for (int d = 0; d < DH; ++d) {
            const float dv = s_dop[h * DH + d];
            const float xv[VPT] = { xa[d].x, xa[d].y, xa[d].z, xa[d].w };
            const float gv[VPT] = { ga[d].x, ga[d].y, ga[d].z, ga[d].w };
            #pragma unroll
            for (int v = 0; v < VPT; ++v) {
                const float lg = xv[v] + gv[v];      // TAU = 1.0
                if (lg > m_lg[v]) { m_lg[v] = lg; mdop[v] = dv; }
                const float ev = __expf(xv[v]);
                ssum[v] += ev;
                wsum[v] += ev * dv;
            }
        }
    }

    // ---- per-voxel vector loads (all float4; n0 % 4 == 0 keeps 16B align) ----
    const float* fl = flow + ((size_t)b * NVOX + (size_t)n0) * 3;
    float fbuf[3 * VPT];
    *(float4*)(fbuf + 0) = *(const float4*)(fl + 0);
    *(float4*)(fbuf + 4) = *(const float4*)(fl + 4);
    *(float4*)(fbuf + 8) = *(const float4*)(fl + 8);

    const float4* xb4 = xyz4 + (size_t)b * NVOX;
    float4 bxyz[VPT];
    #pragma unroll
    for (int v = 0; v < VPT; ++v) bxyz[v] = xb4[n0 + v];

    const float* ob = ori + (size_t)b * 3 * NVOX;
    const float4 oX4 = *(const float4*)(ob + n0);
    const float4 oY4 = *(const float4*)(ob + NVOX + n0);
    const float4 oZ4 = *(const float4*)(ob + 2 * NVOX + n0);
    const float oX[VPT] = { oX4.x, oX4.y, oX4.z, oX4.w };
    const float oY[VPT] = { oY4.x, oY4.y, oY4.z, oY4.w };
    const float oZ[VPT] = { oZ4.x, oZ4.y, oZ4.z, oZ4.w };

    const float4 sg4 = *(const float4*)(seg + (size_t)b * NVOX + n0);
    const float sg[VPT] = { sg4.x, sg4.y, sg4.z, sg4.w };

    // y,z shared by the consecutive-x voxels (VPT divides ELE).
    const int xB = n0 & (ELE - 1);
    const int yI = (n0 >> 5) & (AZI - 1);
    const int zI = n0 >> 12;

    float contrib = 0.0f;
    #pragma unroll
    for (int v = 0; v < VPT; ++v) {
        const float vx = (float)(xB + v) + fbuf[3 * v + 0];
        const float vy = (float)yI       + fbuf[3 * v + 1];
        const float vz = (float)zI       + fbuf[3 * v + 2];

        // reference's normalized-grid round trip, then border clamp
        const float gx = 2.0f * vx / (float)(ELE - 1) - 1.0f;
        const float gy = 2.0f * vy / (float)(AZI - 1) - 1.0f;
        const float gz = 2.0f * vz / (float)(RAN - 1) - 1.0f;
        const float ix = fminf(fmaxf((gx + 1.0f) * 0.5f * (float)(ELE - 1), 0.0f), (float)(ELE - 1));
        const float iy = fminf(fmaxf((gy + 1.0f) * 0.5f * (float)(AZI - 1), 0.0f), (float)(AZI - 1));
        const float iz = fminf(fmaxf((gz + 1.0f) * 0.5f * (float)(RAN - 1), 0.0f), (float)(RAN - 1));

        const float x0f = floorf(ix), y0f = floorf(iy), z0f = floorf(iz);
        const float wx = ix - x0f, wy = iy - y0f, wz = iz - z0f;
        int x0 = (int)x0f; x0 = x0 < 0 ? 0 : (x0 > ELE - 1 ? ELE - 1 : x0);
        int y0 = (int)y0f; y0 = y0 < 0 ? 0 : (y0 > AZI - 1 ? AZI - 1 : y0);
        int z0 = (int)z0f; z0 = z0 < 0 ? 0 : (z0 > RAN - 1 ? RAN - 1 : z0);
        const int x1c = x0 + 1 > ELE - 1 ? ELE - 1 : x0 + 1;
        const int y1c = y0 + 1 > AZI - 1 ? AZI - 1 : y0 + 1;
        const int z1c = z0 + 1 > RAN - 1 ? RAN - 1 : z0 + 1;

        // 8 independent float4 gathers
        const int m00 = (z0  * AZI + y0 ) * ELE;
        const int m01 = (z0  * AZI + y1c) * ELE;
        const int m10 = (z1c * AZI + y0 ) * ELE;
        const int m11 = (z1c * AZI + y1c) * ELE;
        const float4 c000 = xb4[m00 + x0],  c001 = xb4[m00 + x1c];
        const float4 c010 = xb4[m01 + x0],  c011 = xb4[m01 + x1c];
        const float4 c100 = xb4[m10 + x0],  c101 = xb4[m10 + x1c];
        const float4 c110 = xb4[m11 + x0],  c111 = xb4[m11 + x1c];

        const float w000 = (1.0f - wz) * (1.0f - wy) * (1.0f - wx);
        const float w001 = (1.0f - wz) * (1.0f - wy) * wx;
        const float w010 = (1.0f - wz) * wy * (1.0f - wx);
        const float w011 = (1.0f - wz) * wy * wx;
        const float w100 = wz * (1.0f - wy) * (1.0f - wx);
        const float w101 = wz * (1.0f - wy) * wx;
        const float w110 = wz * wy * (1.0f - wx);
        const float w111 = wz * wy * wx;

        const float sX = w000*c000.x + w001*c001.x + w010*c010.x + w011*c011.x
                       + w100*c100.x + w101*c101.x + w110*c110.x + w111*c111.x;
        const float sY = w000*c000.y + w001*c001.y + w010*c010.y + w011*c011.y
                       + w100*c100.y + w101*c101.y + w110*c110.y + w111*c111.y;
        const float sZ = w000*c000.z + w001*c001.z + w010*c010.z + w011*c011.z
                       + w100*c100.z + w101*c101.z + w110*c110.z + w111*c111.z;

        const float vX = (sX - bxyz[v].x) * 10.0f;   // / INTERVAL(0.1)
        const float vY = (sY - bxyz[v].y) * 10.0f;
        const float vZ = (sZ - bxyz[v].z) * 10.0f;
        const float dop_label = vX * oX[v] + vY * oY[v] + vZ * oZ[v];

        const float dop1 = mdop[v];
        const float dop2 = wsum[v] / ssum[v];
        float e1 = dop_label - dop1; e1 *= e1;
        float e2 = dop_label - dop2; e2 *= e2;
        const float seg_label = 0.5f * (sigmoidf_(10.0f * (0.15f - e1)) +
                                        sigmoidf_(10.0f * (0.15f - e2)));
        contrib += fabsf(sigmoidf_(sg[v]) - seg_label);
    }

    // ---- block reduction: wave64 shuffle, then partials in LDS ----
    #pragma unroll
    for (int off = 32; off > 0; off >>= 1)
        contrib += __shfl_down(contrib, off, 64);
    const int lane = threadIdx.x & 63;
    const int wid  = threadIdx.x >> 6;
    if (lane == 0) s_wave[wid] = contrib;
    __syncthreads();
    if (threadIdx.x == 0) {
        float bsum = 0.0f;
        #pragma unroll
        for (int w = 0; w < TPB / 64; ++w) bsum += s_wave[w];
        atomicAdd(out, bsum * (1.0f / ((float)BSZ * (float)NVOX)));
    }
}

extern "C" void kernel_launch(void* const* d_in, const int* in_sizes, int n_in,
                              void* d_out, int out_size, void* d_ws, size_t ws_size,
                              hipStream_t stream) {
    const float* seg    = (const float*)d_in[0];
    const float* flow   = (const float*)d_in[1];
    const float* x1     = (const float*)d_in[2];
    const float* dopar  = (const float*)d_in[3];
    const float* coords = (const float*)d_in[4];
    const float* ori    = (const float*)d_in[5];
    const float* gumb   = (const float*)d_in[6];
    float* out = (float*)d_out;
    float4* xyz4 = (float4*)d_ws;   // BSZ*NVOX*16 B = 16.8 MB

    hipMemsetAsync(d_out, 0, sizeof(float) * (size_t)out_size, stream);

    dim3 gridA(NVOX / (TPB * 4), BSZ);
    xyz_precompute<<<gridA, TPB, 0, stream>>>(coords, xyz4);
    dim3 gridB(NVOX / (TPB * VPT), BSZ);
    seg_dop_loss<<<gridB, TPB, 0, stream>>>(seg, flow, x1, dopar, ori, gumb, xyz4, out);
}

// Round 3
// 327.079 us; speedup vs baseline: 1.0513x; 1.0513x over previous
//
#include <hip/hip_runtime.h>
#include <math.h>

// Problem constants (fixed by the reference).
#define BSZ  2
#define DOPN 32
#define RAN  128   // D (z)
#define AZI  128   // H (y)
#define ELE  32    // W (x)
#define NVOX (RAN * AZI * ELE)   // 524288 voxels per batch
#define TPB  256
#define VPT  2     // voxels per thread in kernel B (2048 blocks -> full TLP)
#define DH   8     // planes per pipeline chunk (8 x1 + 8 gumbels float2 loads)

__device__ __forceinline__ float sigmoidf_(float t) {
    return 1.0f / (1.0f + __expf(-t));
}

// Kernel A: xyz4[b][n] = {x,y,z,0} cartesian of coords. Interleaved float4 so
// kernel B's 8-corner gather is 8x float4 instead of 24 scalar loads.
__global__ __launch_bounds__(TPB) void xyz_precompute(
    const float* __restrict__ coords, float4* __restrict__ xyz4)
{
    const int n0 = (blockIdx.x * TPB + threadIdx.x) * 4;
    const int b = blockIdx.y;
    const float* cb = coords + (size_t)b * 3 * NVOX;
    const float4 r4 = *(const float4*)(cb + n0);
    const float4 a4 = *(const float4*)(cb + NVOX + n0);
    const float4 e4 = *(const float4*)(cb + 2 * NVOX + n0);
    const float rr[4] = { r4.x, r4.y, r4.z, r4.w };
    const float aa[4] = { a4.x, a4.y, a4.z, a4.w };
    const float ee[4] = { e4.x, e4.y, e4.z, e4.w };
    float4* op = xyz4 + (size_t)b * NVOX + n0;
    #pragma unroll
    for (int v = 0; v < 4; ++v) {
        float sa, ca, se, ce;
        __sincosf(aa[v], &sa, &ca);
        __sincosf(ee[v], &se, &ce);
        op[v] = make_float4(rr[v] * ce * ca, rr[v] * ce * sa, rr[v] * se, 0.0f);
    }
}

// Kernel B: per-voxel DOP reduction (argmax of x1+gumbels, softmax(x1)·dop)
// + trilinear warp + loss.
// Latency-bound regime (rocprof: HBM 18%, VALU 13%, 0 conflicts). Lever is
// outstanding-loads per CU: keep the 2048-block grid (full wave occupancy,
// VPT=4 regression proved TLP dominates) and software-pipeline the DOP sweep
// with an explicit double buffer (chunk h+1 issued before consuming chunk h,
// 16-32 loads in flight per wave, all buffer indices compile-time static).
__global__ __launch_bounds__(TPB) void seg_dop_loss(
    const float* __restrict__ seg, const float* __restrict__ flow,
    const float* __restrict__ x1, const float* __restrict__ dop_arr,
    const float* __restrict__ ori, const float* __restrict__ gumbels,
    const float4* __restrict__ xyz4, float* __restrict__ out)
{
    __shared__ float s_dop[DOPN];
    __shared__ float s_wave[TPB / 64];

    const int b = blockIdx.y;
    if (threadIdx.x < DOPN) s_dop[threadIdx.x] = dop_arr[b * DOPN + threadIdx.x];
    __syncthreads();

    const int n0 = (blockIdx.x * TPB + threadIdx.x) * VPT;
    const size_t base = (size_t)b * DOPN * NVOX + (size_t)n0;

    // ---- DOP axis: argmax(x1+gumbels) + unnormalized softmax(x1)·dop ----
    // x1 ~ N(0,1): exp without max-subtraction is fp32-safe and exact here.
    // Track the dop VALUE at the running max (first-max semantics == argmax).
    float m_lg[VPT] = { -3.4e38f, -3.4e38f };
    float mdop[VPT] = { 0.f, 0.f };
    float ssum[VPT] = { 0.f, 0.f };
    float wsum[VPT] = { 0.f, 0.f };

    float2 Ax[DH], Ag[DH], Bx[DH], Bg[DH];

    // Issue one chunk's 16 float2 loads (x and g interleaved per plane).
    #define LOADC(BX, BG, H)                                                   \
        _Pragma("unroll")                                                      \
        for (int d = 0; d < DH; ++d) {                                         \
            const size_t p = base + (size_t)((H) * DH + d) * NVOX;             \
            BX[d] = *(const float2*)(x1 + p);                                  \
            BG[d] = *(const float2*)(gumbels + p);                             \
        }

    // Consume one chunk (ascending dg preserves first-max argmax semantics).
    #define CONSC(BX, BG, H)                                                   \
        _Pragma("unroll")                                                      \
        for (int d = 0; d < DH; ++d) {                                         \
            const float dv = s_dop[(H) * DH + d];                              \
            const float xv[VPT] = { BX[d].x, BX[d].y };                        \
            const float gv[VPT] = { BG[d].x, BG[d].y };                        \
            _Pragma("unroll")                                                  \
            for (int v = 0; v < VPT; ++v) {                                    \
                const float lg = xv[v] + gv[v];      /* TAU = 1.0 */           \
                if (lg > m_lg[v]) { m_lg[v] = lg; mdop[v] = dv; }              \
                const float ev = __expf(xv[v]);                                \
                ssum[v] += ev;                                                 \
                wsum[v] += ev * dv;                                            \
            }                                                                  \
        }

    LOADC(Ax, Ag, 0);      // chunk 0 in flight
    LOADC(Bx, Bg, 1);      // chunk 1 in flight (32 loads outstanding)
    CONSC(Ax, Ag, 0);      // waits only on chunk 0's loads
    LOADC(Ax, Ag, 2);      // refill A while B still in flight
    CONSC(Bx, Bg, 1);
    LOADC(Bx, Bg, 3);
    CONSC(Ax, Ag, 2);
    CONSC(Bx, Bg, 3);

    #undef LOADC
    #undef CONSC

    // ---- per-voxel vector loads (n0 even -> all float2 8B-aligned) ----
    const float* fl = flow + ((size_t)b * NVOX + (size_t)n0) * 3;
    float fbuf[3 * VPT];
    *(float2*)(fbuf)     = *(const float2*)(fl);
    *(float2*)(fbuf + 2) = *(const float2*)(fl + 2);
    *(float2*)(fbuf + 4) = *(const float2*)(fl + 4);

    const float4* xb4 = xyz4 + (size_t)b * NVOX;
    float4 bxyz[VPT];
    #pragma unroll
    for (int v = 0; v < VPT; ++v) bxyz[v] = xb4[n0 + v];

    const float* ob = ori + (size_t)b * 3 * NVOX;
    const float2 oX2 = *(const float2*)(ob + n0);
    const float2 oY2 = *(const float2*)(ob + NVOX + n0);
    const float2 oZ2 = *(const float2*)(ob + 2 * NVOX + n0);
    const float oX[VPT] = { oX2.x, oX2.y };
    const float oY[VPT] = { oY2.x, oY2.y };
    const float oZ[VPT] = { oZ2.x, oZ2.y };

    const float2 sg2 = *(const float2*)(seg + (size_t)b * NVOX + n0);
    const float sg[VPT] = { sg2.x, sg2.y };

    // y,z shared by the consecutive-x voxels (VPT divides ELE).
    const int xB = n0 & (ELE - 1);
    const int yI = (n0 >> 5) & (AZI - 1);
    const int zI = n0 >> 12;

    float contrib = 0.0f;
    #pragma unroll
    for (int v = 0; v < VPT; ++v) {
        const float vx = (float)(xB + v) + fbuf[3 * v + 0];
        const float vy = (float)yI       + fbuf[3 * v + 1];
        const float vz = (float)zI       + fbuf[3 * v + 2];

        // reference's normalized-grid round trip, then border clamp
        const float gx = 2.0f * vx / (float)(ELE - 1) - 1.0f;
        const float gy = 2.0f * vy / (float)(AZI - 1) - 1.0f;
        const float gz = 2.0f * vz / (float)(RAN - 1) - 1.0f;
        const float ix = fminf(fmaxf((gx + 1.0f) * 0.5f * (float)(ELE - 1), 0.0f), (float)(ELE - 1));
        const float iy = fminf(fmaxf((gy + 1.0f) * 0.5f * (float)(AZI - 1), 0.0f), (float)(AZI - 1));
        const float iz = fminf(fmaxf((gz + 1.0f) * 0.5f * (float)(RAN - 1), 0.0f), (float)(RAN - 1));

        const float x0f = floorf(ix), y0f = floorf(iy), z0f = floorf(iz);
        const float wx = ix - x0f, wy = iy - y0f, wz = iz - z0f;
        int x0 = (int)x0f; x0 = x0 < 0 ? 0 : (x0 > ELE - 1 ? ELE - 1 : x0);
        int y0 = (int)y0f; y0 = y0 < 0 ? 0 : (y0 > AZI - 1 ? AZI - 1 : y0);
        int z0 = (int)z0f; z0 = z0 < 0 ? 0 : (z0 > RAN - 1 ? RAN - 1 : z0);
        const int x1c = x0 + 1 > ELE - 1 ? ELE - 1 : x0 + 1;
        const int y1c = y0 + 1 > AZI - 1 ? AZI - 1 : y0 + 1;
        const int z1c = z0 + 1 > RAN - 1 ? RAN - 1 : z0 + 1;

        // 8 independent float4 gathers
        const int m00 = (z0  * AZI + y0 ) * ELE;
        const int m01 = (z0  * AZI + y1c) * ELE;
        const int m10 = (z1c * AZI + y0 ) * ELE;
        const int m11 = (z1c * AZI + y1c) * ELE;
        const float4 c000 = xb4[m00 + x0],  c001 = xb4[m00 + x1c];
        const float4 c010 = xb4[m01 + x0],  c011 = xb4[m01 + x1c];
        const float4 c100 = xb4[m10 + x0],  c101 = xb4[m10 + x1c];
        const float4 c110 = xb4[m11 + x0],  c111 = xb4[m11 + x1c];

        const float w000 = (1.0f - wz) * (1.0f - wy) * (1.0f - wx);
        const float w001 = (1.0f - wz) * (1.0f - wy) * wx;
        const float w010 = (1.0f - wz) * wy * (1.0f - wx);
        const float w011 = (1.0f - wz) * wy * wx;
        const float w100 = wz * (1.0f - wy) * (1.0f - wx);
        const float w101 = wz * (1.0f - wy) * wx;
        const float w110 = wz * wy * (1.0f - wx);
        const float w111 = wz * wy * wx;

        const float sX = w000*c000.x + w001*c001.x + w010*c010.x + w011*c011.x
                       + w100*c100.x + w101*c101.x + w110*c110.x + w111*c111.x;
        const float sY = w000*c000.y + w001*c001.y + w010*c010.y + w011*c011.y
                       + w100*c100.y + w101*c101.y + w110*c110.y + w111*c111.y;
        const float sZ = w000*c000.z + w001*c001.z + w010*c010.z + w011*c011.z
                       + w100*c100.z + w101*c101.z + w110*c110.z + w111*c111.z;

        const float vX = (sX - bxyz[v].x) * 10.0f;   // / INTERVAL(0.1)
        const float vY = (sY - bxyz[v].y) * 10.0f;
        const float vZ = (sZ - bxyz[v].z) * 10.0f;
        const float dop_label = vX * oX[v] + vY * oY[v] + vZ * oZ[v];

        const float dop1 = mdop[v];
        const float dop2 = wsum[v] / ssum[v];
        float e1 = dop_label - dop1; e1 *= e1;
        float e2 = dop_label - dop2; e2 *= e2;
        const float seg_label = 0.5f * (sigmoidf_(10.0f * (0.15f - e1)) +
                                        sigmoidf_(10.0f * (0.15f - e2)));
        contrib += fabsf(sigmoidf_(sg[v]) - seg_label);
    }

    // ---- block reduction: wave64 shuffle, then partials in LDS ----
    #pragma unroll
    for (int off = 32; off > 0; off >>= 1)
        contrib += __shfl_down(contrib, off, 64);
    const int lane = threadIdx.x & 63;
    const int wid  = threadIdx.x >> 6;
    if (lane == 0) s_wave[wid] = contrib;
    __syncthreads();
    if (threadIdx.x == 0) {
        float bsum = 0.0f;
        #pragma unroll
        for (int w = 0; w < TPB / 64; ++w) bsum += s_wave[w];
        atomicAdd(out, bsum * (1.0f / ((float)BSZ * (float)NVOX)));
    }
}

extern "C" void kernel_launch(void* const* d_in, const int* in_sizes, int n_in,
                              void* d_out, int out_size, void* d_ws, size_t ws_size,
                              hipStream_t stream) {
    const float* seg    = (const float*)d_in[0];
    const float* flow   = (const float*)d_in[1];
    const float* x1     = (const float*)d_in[2];
    const float* dopar  = (const float*)d_in[3];
    const float* coords = (const float*)d_in[4];
    const float* ori    = (const float*)d_in[5];
    const float* gumb   = (const float*)d_in[6];
    float* out = (float*)d_out;
    float4* xyz4 = (float4*)d_ws;   // BSZ*NVOX*16 B = 16.8 MB

    hipMemsetAsync(d_out, 0, sizeof(float) * (size_t)out_size, stream);

    dim3 gridA(NVOX / (TPB * 4), BSZ);
    xyz_precompute<<<gridA, TPB, 0, stream>>>(coords, xyz4);
    dim3 gridB(NVOX / (TPB * VPT), BSZ);
    seg_dop_loss<<<gridB, TPB, 0, stream>>>(seg, flow, x1, dopar, ori, gumb, xyz4, out);
}

// Round 4
// 324.530 us; speedup vs baseline: 1.0596x; 1.0079x over previous
//
#include <hip/hip_runtime.h>
#include <math.h>

// Problem constants (fixed by the reference).
#define BSZ  2
#define DOPN 32
#define RAN  128   // D (z)
#define AZI  128   // H (y)
#define ELE  32    // W (x)
#define NVOX (RAN * AZI * ELE)   // 524288 voxels per batch
#define TPB  256
#define VPT  2     // voxels per thread (2048 blocks == exactly fills 8192 wave slots)
#define DH   8     // planes per chunk (8 float4 stream loads in flight)

__device__ __forceinline__ float sigmoidf_(float t) {
    return 1.0f / (1.0f + __expf(-t));
}

// Kernel A: xyz4[b][n] = {x,y,z,0} cartesian of coords. Interleaved float4 so
// kernel B's 8-corner gather is 8x float4 instead of 24 scalar loads.
// Block (0,0) also zeroes the output accumulator (replaces the memset dispatch).
__global__ __launch_bounds__(TPB) void xyz_precompute(
    const float* __restrict__ coords, float4* __restrict__ xyz4,
    float* __restrict__ out, int out_elems)
{
    if (blockIdx.x == 0 && blockIdx.y == 0) {
        for (int i = threadIdx.x; i < out_elems; i += TPB) out[i] = 0.0f;
    }
    const int n0 = (blockIdx.x * TPB + threadIdx.x) * 4;
    const int b = blockIdx.y;
    const float* cb = coords + (size_t)b * 3 * NVOX;
    const float4 r4 = *(const float4*)(cb + n0);
    const float4 a4 = *(const float4*)(cb + NVOX + n0);
    const float4 e4 = *(const float4*)(cb + 2 * NVOX + n0);
    const float rr[4] = { r4.x, r4.y, r4.z, r4.w };
    const float aa[4] = { a4.x, a4.y, a4.z, a4.w };
    const float ee[4] = { e4.x, e4.y, e4.z, e4.w };
    float4* op = xyz4 + (size_t)b * NVOX + n0;
    #pragma unroll
    for (int v = 0; v < 4; ++v) {
        float sa, ca, se, ce;
        __sincosf(aa[v], &sa, &ca);
        __sincosf(ee[v], &se, &ce);
        op[v] = make_float4(rr[v] * ce * ca, rr[v] * ce * sa, rr[v] * se, 0.0f);
    }
}

// Kernel B: per-voxel DOP reduction (argmax of x1+gumbels, softmax(x1)·dop)
// + trilinear warp + loss.
// Latency/issue-bound regime (HBM 18%, VALU 13%, 0 conflicts, VGPR 36).
// The compiler pins in-flight loads per wave regardless of source order
// (R3: explicit dbuf flattened back to 36 VGPR). So the lever is VMEM
// instruction COUNT at constant wave count: lane-pairs cooperatively stream
// x1/gumbels as float4 (even lane loads x1 for 4 voxels, odd lane gumbels),
// exchanging halves via 2x __shfl_xor (DPP quad-perm, no LDS/barrier).
// Sweep VMEM: 64 -> 32 instrs/thread; per-voxel math and reduction order are
// bit-identical to the verified 322us kernel.
__global__ __launch_bounds__(TPB) void seg_dop_loss(
    const float* __restrict__ seg, const float* __restrict__ flow,
    const float* __restrict__ x1, const float* __restrict__ dop_arr,
    const float* __restrict__ ori, const float* __restrict__ gumbels,
    const float4* __restrict__ xyz4, float* __restrict__ out)
{
    __shared__ float s_dop[DOPN];
    __shared__ float s_wave[TPB / 64];

    const int b = blockIdx.y;
    if (threadIdx.x < DOPN) s_dop[threadIdx.x] = dop_arr[b * DOPN + threadIdx.x];
    __syncthreads();

    const int n0 = (blockIdx.x * TPB + threadIdx.x) * VPT;

    // ---- DOP axis: argmax(x1+gumbels) + unnormalized softmax(x1)·dop ----
    // x1 ~ N(0,1): exp without max-subtraction is fp32-safe and exact here.
    // Track the dop VALUE at the running max (first-max semantics == argmax).
    float m_lg[VPT] = { -3.4e38f, -3.4e38f };
    float mdop[VPT] = { 0.f, 0.f };
    float ssum[VPT] = { 0.f, 0.f };
    float wsum[VPT] = { 0.f, 0.f };

    // Pair-cooperative stream: lane pair (t, t^1) shares a 4-voxel group.
    // Even lane streams x1[group], odd lane streams gumbels[group], float4.
    const int par = threadIdx.x & 1;          // 0: x1 carrier, 1: gumbels carrier
    const int cg  = n0 & ~3;                  // group column (n0 for even, n0-2 for odd)
    const float* swp = par ? gumbels : x1;
    const size_t sbase = (size_t)b * DOPN * NVOX + (size_t)cg;

    float4 q[DH];
    for (int h = 0; h < DOPN / DH; ++h) {     // runtime loop: regs reused
        #pragma unroll
        for (int d = 0; d < DH; ++d)
            q[d] = *(const float4*)(swp + sbase + (size_t)(h * DH + d) * NVOX);
        #pragma unroll
        for (int d = 0; d < DH; ++d) {
            const float dv = s_dop[h * DH + d];
            // exchange: even sends q.zw (x1 for odd's voxels), odd sends q.xy
            // (gumbels for even's voxels); one shfl_xor carries both directions.
            const float t0 = par ? q[d].x : q[d].z;
            const float t1 = par ? q[d].y : q[d].w;
            const float r0 = __shfl_xor(t0, 1, 64);
            const float r1 = __shfl_xor(t1, 1, 64);
            const float xv[VPT] = { par ? r0 : q[d].x, par ? r1 : q[d].y };
            const float gv[VPT] = { par ? q[d].z : r0, par ? q[d].w : r1 };
            #pragma unroll
            for (int v = 0; v < VPT; ++v) {
                const float lg = xv[v] + gv[v];      // TAU = 1.0
                if (lg > m_lg[v]) { m_lg[v] = lg; mdop[v] = dv; }
                const float ev = __expf(xv[v]);
                ssum[v] += ev;
                wsum[v] += ev * dv;
            }
        }
    }

    // ---- per-voxel vector loads (n0 even -> all float2 8B-aligned) ----
    const float* fl = flow + ((size_t)b * NVOX + (size_t)n0) * 3;
    float fbuf[3 * VPT];
    *(float2*)(fbuf)     = *(const float2*)(fl);
    *(float2*)(fbuf + 2) = *(const float2*)(fl + 2);
    *(float2*)(fbuf + 4) = *(const float2*)(fl + 4);

    const float4* xb4 = xyz4 + (size_t)b * NVOX;
    float4 bxyz[VPT];
    #pragma unroll
    for (int v = 0; v < VPT; ++v) bxyz[v] = xb4[n0 + v];

    const float* ob = ori + (size_t)b * 3 * NVOX;
    const float2 oX2 = *(const float2*)(ob + n0);
    const float2 oY2 = *(const float2*)(ob + NVOX + n0);
    const float2 oZ2 = *(const float2*)(ob + 2 * NVOX + n0);
    const float oX[VPT] = { oX2.x, oX2.y };
    const float oY[VPT] = { oY2.x, oY2.y };
    const float oZ[VPT] = { oZ2.x, oZ2.y };

    const float2 sg2 = *(const float2*)(seg + (size_t)b * NVOX + n0);
    const float sg[VPT] = { sg2.x, sg2.y };

    // y,z shared by the consecutive-x voxels (VPT divides ELE).
    const int xB = n0 & (ELE - 1);
    const int yI = (n0 >> 5) & (AZI - 1);
    const int zI = n0 >> 12;

    float contrib = 0.0f;
    #pragma unroll
    for (int v = 0; v < VPT; ++v) {
        const float vx = (float)(xB + v) + fbuf[3 * v + 0];
        const float vy = (float)yI       + fbuf[3 * v + 1];
        const float vz = (float)zI       + fbuf[3 * v + 2];

        // reference's normalized-grid round trip, then border clamp
        const float gx = 2.0f * vx / (float)(ELE - 1) - 1.0f;
        const float gy = 2.0f * vy / (float)(AZI - 1) - 1.0f;
        const float gz = 2.0f * vz / (float)(RAN - 1) - 1.0f;
        const float ix = fminf(fmaxf((gx + 1.0f) * 0.5f * (float)(ELE - 1), 0.0f), (float)(ELE - 1));
        const float iy = fminf(fmaxf((gy + 1.0f) * 0.5f * (float)(AZI - 1), 0.0f), (float)(AZI - 1));
        const float iz = fminf(fmaxf((gz + 1.0f) * 0.5f * (float)(RAN - 1), 0.0f), (float)(RAN - 1));

        const float x0f = floorf(ix), y0f = floorf(iy), z0f = floorf(iz);
        const float wx = ix - x0f, wy = iy - y0f, wz = iz - z0f;
        int x0 = (int)x0f; x0 = x0 < 0 ? 0 : (x0 > ELE - 1 ? ELE - 1 : x0);
        int y0 = (int)y0f; y0 = y0 < 0 ? 0 : (y0 > AZI - 1 ? AZI - 1 : y0);
        int z0 = (int)z0f; z0 = z0 < 0 ? 0 : (z0 > RAN - 1 ? RAN - 1 : z0);
        const int x1c = x0 + 1 > ELE - 1 ? ELE - 1 : x0 + 1;
        const int y1c = y0 + 1 > AZI - 1 ? AZI - 1 : y0 + 1;
        const int z1c = z0 + 1 > RAN - 1 ? RAN - 1 : z0 + 1;

        // 8 independent float4 gathers
        const int m00 = (z0  * AZI + y0 ) * ELE;
        const int m01 = (z0  * AZI + y1c) * ELE;
        const int m10 = (z1c * AZI + y0 ) * ELE;
        const int m11 = (z1c * AZI + y1c) * ELE;
        const float4 c000 = xb4[m00 + x0],  c001 = xb4[m00 + x1c];
        const float4 c010 = xb4[m01 + x0],  c011 = xb4[m01 + x1c];
        const float4 c100 = xb4[m10 + x0],  c101 = xb4[m10 + x1c];
        const float4 c110 = xb4[m11 + x0],  c111 = xb4[m11 + x1c];

        const float w000 = (1.0f - wz) * (1.0f - wy) * (1.0f - wx);
        const float w001 = (1.0f - wz) * (1.0f - wy) * wx;
        const float w010 = (1.0f - wz) * wy * (1.0f - wx);
        const float w011 = (1.0f - wz) * wy * wx;
        const float w100 = wz * (1.0f - wy) * (1.0f - wx);
        const float w101 = wz * (1.0f - wy) * wx;
        const float w110 = wz * wy * (1.0f - wx);
        const float w111 = wz * wy * wx;

        const float sX = w000*c000.x + w001*c001.x + w010*c010.x + w011*c011.x
                       + w100*c100.x + w101*c101.x + w110*c110.x + w111*c111.x;
        const float sY = w000*c000.y + w001*c001.y + w010*c010.y + w011*c011.y
                       + w100*c100.y + w101*c101.y + w110*c110.y + w111*c111.y;
        const float sZ = w000*c000.z + w001*c001.z + w010*c010.z + w011*c011.z
                       + w100*c100.z + w101*c101.z + w110*c110.z + w111*c111.z;

        const float vX = (sX - bxyz[v].x) * 10.0f;   // / INTERVAL(0.1)
        const float vY = (sY - bxyz[v].y) * 10.0f;
        const float vZ = (sZ - bxyz[v].z) * 10.0f;
        const float dop_label = vX * oX[v] + vY * oY[v] + vZ * oZ[v];

        const float dop1 = mdop[v];
        const float dop2 = wsum[v] / ssum[v];
        float e1 = dop_label - dop1; e1 *= e1;
        float e2 = dop_label - dop2; e2 *= e2;
        const float seg_label = 0.5f * (sigmoidf_(10.0f * (0.15f - e1)) +
                                        sigmoidf_(10.0f * (0.15f - e2)));
        contrib += fabsf(sigmoidf_(sg[v]) - seg_label);
    }

    // ---- block reduction: wave64 shuffle, then partials in LDS ----
    #pragma unroll
    for (int off = 32; off > 0; off >>= 1)
        contrib += __shfl_down(contrib, off, 64);
    const int lane = threadIdx.x & 63;
    const int wid  = threadIdx.x >> 6;
    if (lane == 0) s_wave[wid] = contrib;
    __syncthreads();
    if (threadIdx.x == 0) {
        float bsum = 0.0f;
        #pragma unroll
        for (int w = 0; w < TPB / 64; ++w) bsum += s_wave[w];
        atomicAdd(out, bsum * (1.0f / ((float)BSZ * (float)NVOX)));
    }
}

extern "C" void kernel_launch(void* const* d_in, const int* in_sizes, int n_in,
                              void* d_out, int out_size, void* d_ws, size_t ws_size,
                              hipStream_t stream) {
    const float* seg    = (const float*)d_in[0];
    const float* flow   = (const float*)d_in[1];
    const float* x1     = (const float*)d_in[2];
    const float* dopar  = (const float*)d_in[3];
    const float* coords = (const float*)d_in[4];
    const float* ori    = (const float*)d_in[5];
    const float* gumb   = (const float*)d_in[6];
    float* out = (float*)d_out;
    float4* xyz4 = (float4*)d_ws;   // BSZ*NVOX*16 B = 16.8 MB

    dim3 gridA(NVOX / (TPB * 4), BSZ);
    xyz_precompute<<<gridA, TPB, 0, stream>>>(coords, xyz4, out, out_size);
    dim3 gridB(NVOX / (TPB * VPT), BSZ);
    seg_dop_loss<<<gridB, TPB, 0, stream>>>(seg, flow, x1, dopar, ori, gumb, xyz4, out);
}